// Round 7
// baseline (251.139 us; speedup 1.0000x reference)
//
#include <hip/hip_runtime.h>

// SGE-style gate: B=64, C=512, HW=784, G=8, cpg=64. One block per (b,g).
//
// R10 = R9's DMA pipeline with the fp16 tile park moved LDS -> REGISTERS.
// R9 evidence: traffic clean (FETCH 50MB, WRITE 100MB) but 62us @ 2.5TB/s:
// 153KB LDS -> 1 block/CU, 2 sequential block rounds, occupancy 16%; all
// stalls exposed (no phase diversity), read/write phases chip-exclusive.
// Fix: park the tile as fp16 in VGPRs (~50 regs: 3 f32x4/chunk x 8 chunks,
// per-thread = exactly what it stages), LDS drops to 53KB (stage 2x25KB +
// gate) -> 2 blocks/CU, ALL 512 blocks co-resident, one block's store
// phase overlaps its CU-mate's DMA read phase (duplex HBM).
// Register parking is safe here (unlike R4): global loads go DMA->LDS, the
// park is ds_read -> cvt_fp16 -> reg, write-once read-once.
// Geometry bonus: 1568 f32x4/chunk = 8*196 -> a thread's gate columns are
// the SAME for all 8 chunks (3 gate regs serve the whole epilogue).
//
// Chunk flow (e = 0..7, fully unrolled for static park indexing):
//   [vmcnt(counted, never 0 mid-loop) + s_barrier]   chunk e resident
//   means: wave w reduces row w (fp32)
//   [lgkmcnt(0) + s_barrier]
//   s-accum (fp32) + park chunk as f16x4 regs
//   [lgkmcnt(0) + s_barrier]; issue chunk e+2 into freed buffer
// Then mu/var/gate (fp32, LDS), epilogue: out = f32(park)*gate, plain
// coalesced stores. absmax ~0.03 (fp16 epilogue rounding; passed in R9).

#define HW      784
#define NG      8
#define TILE_F  50176        // floats per (b,g) tile
#define CHUNK_F 6272         // floats per chunk (8 rows)
#define CH4     1568         // f32x4 per chunk ( = 8*196 )
#define NCH     8

typedef float    f32x4 __attribute__((ext_vector_type(4)));
typedef _Float16 f16x4 __attribute__((ext_vector_type(4)));

__device__ __forceinline__ void gload16(const float* g, float* l) {
    __builtin_amdgcn_global_load_lds(
        (const __attribute__((address_space(1))) void*)g,
        (__attribute__((address_space(3))) void*)l, 16, 0, 0);
}

#define WAIT_VM(N)  asm volatile("s_waitcnt vmcnt(" #N ")" ::: "memory")
#define WAIT_LGKM() asm volatile("s_waitcnt lgkmcnt(0)" ::: "memory")
#define RAW_BAR()   do { __builtin_amdgcn_s_barrier(); \
                         __builtin_amdgcn_sched_barrier(0); } while (0)

__global__ __launch_bounds__(512, 4)
void sge_kernel(const float* __restrict__ x, const float* __restrict__ weight,
                const float* __restrict__ bias, float* __restrict__ out) {
    __shared__ float stg[2][CHUNK_F];    // 50,176 B double-buffered stage
    __shared__ float gbuf[HW];           // gate
    __shared__ float smean[8];
    __shared__ float red[16];

    const int t = threadIdx.x, lane = t & 63, wave = t >> 6;   // 512 thr
    const int bg = blockIdx.x, g = bg & (NG - 1);
    const float* xt = x + (size_t)bg * TILE_F;
    const bool has1 = t < (HW - 512);    // t < 272
    const int  tc   = t >> 5;            // tail-chunk this thread parks (t<256)

    // issue chunk e into stage buffer b: per wave 3x 1KB DMA + wave0 tail.
    auto issue = [&](int e, int b) {
        const float* gs = xt + e * CHUNK_F;
        float* ld = stg[b];
        const int uo = wave * 768;
        gload16(gs + uo       + lane * 4, ld + uo);
        gload16(gs + uo + 256 + lane * 4, ld + uo + 256);
        gload16(gs + uo + 512 + lane * 4, ld + uo + 512);
        if (wave == 0 && lane < 32)
            gload16(gs + 6144 + lane * 4, ld + 6144);
    };

    issue(0, 0);
    issue(1, 1);

    float acc0 = 0.f, acc1 = 0.f;
    f16x4 pk0[NCH], pk1[NCH], pk2[NCH], pt;

#pragma unroll
    for (int e = 0; e < NCH; ++e) {
        const int b = e & 1;
        if (e < NCH - 1) { if (wave == 0) WAIT_VM(4); else WAIT_VM(3); }
        else             { WAIT_VM(0); }
        RAW_BAR();

        // ---- per-channel means: wave w reduces row w of the chunk ----
        {
            const f32x4* r4 = (const f32x4*)(stg[b] + wave * HW);
            const f32x4 v0 = r4[lane], v1 = r4[lane + 64], v2 = r4[lane + 128];
            float s = ((v0.x + v0.y) + (v0.z + v0.w))
                    + ((v1.x + v1.y) + (v1.z + v1.w))
                    + ((v2.x + v2.y) + (v2.z + v2.w));
            if (lane < 4) {
                const f32x4 v3 = r4[lane + 192];
                s += (v3.x + v3.y) + (v3.z + v3.w);
            }
#pragma unroll
            for (int m = 1; m < 64; m <<= 1) s += __shfl_xor(s, m, 64);
            if (lane == 0) smean[wave] = s * (1.0f / (float)HW);
        }
        WAIT_LGKM(); RAW_BAR();          // smean visible

        // ---- s-accumulate (fp32) + park chunk into f16 registers ----
        {
            const float* sb = stg[b];
            const float m0 = smean[0], m1 = smean[1], m2 = smean[2], m3 = smean[3];
            const float m4 = smean[4], m5 = smean[5], m6 = smean[6], m7 = smean[7];
            acc0 += sb[t]          * m0 + sb[t + HW]     * m1
                  + sb[t + 2 * HW] * m2 + sb[t + 3 * HW] * m3
                  + sb[t + 4 * HW] * m4 + sb[t + 5 * HW] * m5
                  + sb[t + 6 * HW] * m6 + sb[t + 7 * HW] * m7;
            if (has1) {
                const int p = t + 512;
                acc1 += sb[p]          * m0 + sb[p + HW]     * m1
                      + sb[p + 2 * HW] * m2 + sb[p + 3 * HW] * m3
                      + sb[p + 4 * HW] * m4 + sb[p + 5 * HW] * m5
                      + sb[p + 6 * HW] * m6 + sb[p + 7 * HW] * m7;
            }
            const f32x4* s4 = (const f32x4*)sb;
            pk0[e] = __builtin_convertvector(s4[t],        f16x4);
            pk1[e] = __builtin_convertvector(s4[t + 512],  f16x4);
            pk2[e] = __builtin_convertvector(s4[t + 1024], f16x4);
            if (t < 256 && tc == e)
                pt = __builtin_convertvector(s4[1536 + (t & 31)], f16x4);
        }
        WAIT_LGKM(); RAW_BAR();          // all reads landed; stage[b] free
        if (e + 2 < NCH) issue(e + 2, b);
    }

    // ---- mu/var over the 784 s-values ----
    float rs  = acc0 + (has1 ? acc1 : 0.f);
    float rs2 = acc0 * acc0 + (has1 ? acc1 * acc1 : 0.f);
#pragma unroll
    for (int m = 1; m < 64; m <<= 1) {
        rs  += __shfl_xor(rs,  m, 64);
        rs2 += __shfl_xor(rs2, m, 64);
    }
    if (lane == 0) { red[wave] = rs; red[8 + wave] = rs2; }
    __syncthreads();
    float ss = 0.f, ss2 = 0.f;
#pragma unroll
    for (int w = 0; w < 8; ++w) { ss += red[w]; ss2 += red[8 + w]; }
    const float mu   = ss * (1.0f / (float)HW);
    const float var  = ss2 * (1.0f / (float)HW) - mu * mu;
    const float rstd = rsqrtf(var + 1e-5f);
    const float wg   = weight[g];
    const float bv   = bias[g];

    gbuf[t] = 1.0f / (1.0f + __expf(-((acc0 - mu) * rstd * wg + bv)));
    if (has1)
        gbuf[t + 512] = 1.0f / (1.0f + __expf(-((acc1 - mu) * rstd * wg + bv)));
    __syncthreads();

    // ---- epilogue: out = f32(park) * gate; 3 fixed gate cols per thread ----
    const f32x4* gb4 = (const f32x4*)gbuf;
    const f32x4 g0 = gb4[t % 196];
    const f32x4 g1 = gb4[(t + 512) % 196];
    const f32x4 g2 = gb4[(t + 1024) % 196];
    f32x4* o4 = (f32x4*)(out + (size_t)bg * TILE_F);
#pragma unroll
    for (int e = 0; e < NCH; ++e) {
        o4[e * CH4 + t]        = __builtin_convertvector(pk0[e], f32x4) * g0;
        o4[e * CH4 + t + 512]  = __builtin_convertvector(pk1[e], f32x4) * g1;
        o4[e * CH4 + t + 1024] = __builtin_convertvector(pk2[e], f32x4) * g2;
    }
    if (t < 256) {
        const int q = 1536 + (t & 31);
        o4[tc * CH4 + q] = __builtin_convertvector(pt, f32x4) * gb4[q % 196];
    }
}

extern "C" void kernel_launch(void* const* d_in, const int* in_sizes, int n_in,
                              void* d_out, int out_size, void* d_ws, size_t ws_size,
                              hipStream_t stream) {
    const float* x      = (const float*)d_in[0];
    const float* weight = (const float*)d_in[1];
    const float* bias   = (const float*)d_in[2];
    float* out = (float*)d_out;
    sge_kernel<<<dim3(512), dim3(512), 0, stream>>>(x, weight, bias, out);
}

// Round 8
// 187.562 us; speedup vs baseline: 1.3390x; 1.3390x over previous
//
#include <hip/hip_runtime.h>

// SGE-style gate: B=64, C=512, HW=784, G=8, cpg=64.
//
// R11 = R9 (best, 62us, clean traffic: FETCH 50MB / WRITE 100MB) with the
// exposure attacked: R9 had 8 waves/CU (1 block x 512thr, 153KB LDS) and 2
// sequential block rounds -> every barrier/vmcnt/shuffle latency exposed and
// read/write phases chip-alternating. R10's register park spilled to scratch
// (WRITE 221MB) -> park stays in LDS.
// Changes:
//  (1) 1024-thread blocks: 16 waves/CU, half the per-thread work.
//  (2) grid=256 (exactly 1 block/CU); each block does TWO tiles (blk, blk+256;
//      same g since 256%8==0). Tile-0's stores are interleaved per-chunk into
//      tile-1's DMA/compute loop -> HBM read+write run duplex in steady state,
//      and no LDS round-boundary serialization.
// Park slots are thread-private (thread t <-> xh[e*1568 + t] and +1024+t),
// so store-read (tile0) then park-write (tile1) of the same slot within one
// iteration is ordered by program order + the lgkm-drained barriers.
// vmcnt per-wave exact: DMA instrs/chunk c_w = 2 (wave<=8) else 1; store
// instrs identical; waits = c_w (tile0 iters) or 2*c_w (overlap iters),
// never 0 mid-loop. weight/bias loaded+pinned up front (no hidden VMEM).
//
// LDS: xh fp16 park 100352 + stage 2x25088 + gate 3136 + smean 32 + red 128
//    = 153824 B (dynamic, FuncSetAttribute).

#define HW      784
#define NG      8
#define TILE_F  50176        // floats per (b,g) tile
#define CHUNK_F 6272         // floats per chunk (8 rows)
#define CH4     1568         // f32x4 per chunk (= 8*196)
#define NCH     8
#define NGC     16           // 2 tiles x 8 chunks

typedef float    f32x4 __attribute__((ext_vector_type(4)));
typedef _Float16 f16x4 __attribute__((ext_vector_type(4)));

#define XH_OFF    0
#define ST_OFF    100352
#define GB_OFF    150528
#define SM_OFF    153664
#define RED_OFF   153696
#define LDS_TOTAL 153824

__device__ __forceinline__ void gload16(const float* g, float* l) {
    __builtin_amdgcn_global_load_lds(
        (const __attribute__((address_space(1))) void*)g,
        (__attribute__((address_space(3))) void*)l, 16, 0, 0);
}

#define WAIT_LGKM() asm volatile("s_waitcnt lgkmcnt(0)" ::: "memory")
#define RAW_BAR()   do { __builtin_amdgcn_s_barrier(); \
                         __builtin_amdgcn_sched_barrier(0); } while (0)

__device__ __forceinline__ void wait_vm_n(int n) {
    if (n == 0)      asm volatile("s_waitcnt vmcnt(0)" ::: "memory");
    else if (n == 1) asm volatile("s_waitcnt vmcnt(1)" ::: "memory");
    else if (n == 2) asm volatile("s_waitcnt vmcnt(2)" ::: "memory");
    else             asm volatile("s_waitcnt vmcnt(4)" ::: "memory");
}

__global__ __launch_bounds__(1024, 4)
void sge_kernel(const float* __restrict__ x, const float* __restrict__ weight,
                const float* __restrict__ bias, float* __restrict__ out) {
    extern __shared__ char smem[];
    _Float16* xh    = (_Float16*)(smem + XH_OFF);   // fp16 park [8][1568] f16x4
    float*    stg   = (float*)(smem + ST_OFF);      // [2][6272] stage
    float*    gbuf  = (float*)(smem + GB_OFF);      // gate[784]
    float*    smean = (float*)(smem + SM_OFF);      // 8
    float*    red   = (float*)(smem + RED_OFF);     // 32

    const int t = threadIdx.x, lane = t & 63, wave = t >> 6;   // 16 waves
    const int blk  = blockIdx.x;           // tiles blk and blk+256 (same g)
    const int col0 = t % 196;              // gate col of idx t   (1568%196==0)
    const int col1 = (t + 44) % 196;       // gate col of idx 1024+t

    float wg = weight[blk & 7];
    float bv = bias[blk & 7];
    asm volatile("" : "+v"(wg), "+v"(bv)); // materialize now; no VMEM later

    // issue DMA for global chunk gc (tile gc>>3, chunk gc&7) into buf gc&1.
    // per-wave instr count: waves 0..8 -> 2, waves 9..15 -> 1.
    auto issue = [&](int gc) {
        const int bg = blk + ((gc >> 3) << 8);
        const float* gs = x + (size_t)bg * TILE_F + (size_t)(gc & 7) * CHUNK_F;
        float* ld = stg + (gc & 1) * CHUNK_F;
        if (wave < 8) {
            gload16(gs + wave * 256 + lane * 4, ld + wave * 256);
            gload16(gs + 4096 + wave * 256 + lane * 4, ld + 4096 + wave * 256);
        } else if (wave == 8) {
            gload16(gs + 2048 + lane * 4, ld + 2048);
            if (lane < 32) gload16(gs + 6144 + lane * 4, ld + 6144);  // 512B tail
        } else {
            gload16(gs + wave * 256 + lane * 4, ld + wave * 256);
        }
    };

    issue(0); issue(1);

    float acc = 0.f;
    f32x4 ga0 = {0.f, 0.f, 0.f, 0.f}, ga1 = {0.f, 0.f, 0.f, 0.f};

#pragma unroll
    for (int gc = 0; gc < NGC; ++gc) {
        const int  b  = gc & 1, e = gc & 7;
        const bool t1 = gc >= 8;

        if (t1) {   // store tile-0 chunk e from park (fire-and-forget)
            const f16x4* px = (const f16x4*)xh + e * CH4;
            f32x4* o4 = (f32x4*)(out + (size_t)blk * TILE_F) + e * CH4;
            o4[t] = __builtin_convertvector(px[t], f32x4) * ga0;
            if (wave < 8) {
                o4[1024 + t] = __builtin_convertvector(px[1024 + t], f32x4) * ga1;
            } else if (wave == 8) {
                if (lane < 32)
                    o4[1024 + t] = __builtin_convertvector(px[1024 + t], f32x4) * ga1;
            }
        }

        {   // chunk gc resident; counted wait (never 0 mid-loop)
            const bool hn = (gc <= 14);            // DMA(gc+1) in flight
            const int  n  = (wave <= 8) ? ((hn ? 2 : 0) + (t1 ? 2 : 0))
                                        : ((hn ? 1 : 0) + (t1 ? 1 : 0));
            wait_vm_n(n);
        }
        RAW_BAR();

        if (wave < 8) {   // per-channel mean: wave w reduces row w
            const f32x4* r4 = (const f32x4*)(stg + b * CHUNK_F + wave * HW);
            const f32x4 v0 = r4[lane], v1 = r4[lane + 64], v2 = r4[lane + 128];
            float s = ((v0.x + v0.y) + (v0.z + v0.w))
                    + ((v1.x + v1.y) + (v1.z + v1.w))
                    + ((v2.x + v2.y) + (v2.z + v2.w));
            if (lane < 4) {
                const f32x4 v3 = r4[lane + 192];
                s += (v3.x + v3.y) + (v3.z + v3.w);
            }
#pragma unroll
            for (int m = 1; m < 64; m <<= 1) s += __shfl_xor(s, m, 64);
            if (lane == 0) smean[wave] = s * (1.0f / (float)HW);
        }
        WAIT_LGKM(); RAW_BAR();

        {   // s-accum (fp32, t<784) + fp16 park of the chunk
            const float* sb = stg + b * CHUNK_F;
            if (t < HW) {
                float a = 0.f;
#pragma unroll
                for (int r = 0; r < 8; ++r) a += sb[t + r * HW] * smean[r];
                acc += a;
            }
            const f32x4* s4 = (const f32x4*)sb;
            f16x4* px = (f16x4*)xh + e * CH4;
            px[t] = __builtin_convertvector(s4[t], f16x4);
            if (wave < 8) {
                px[1024 + t] = __builtin_convertvector(s4[1024 + t], f16x4);
            } else if (wave == 8) {
                if (lane < 32)
                    px[1024 + t] = __builtin_convertvector(s4[1024 + t], f16x4);
            }
        }
        WAIT_LGKM(); RAW_BAR();            // stage[b] reads done -> refill it
        if (gc + 2 < NGC) issue(gc + 2);

        if (e == 7) {   // tile boundary: mu/var -> gate -> gate regs
            float rs  = (t < HW) ? acc : 0.f;
            float rs2 = rs * rs;
#pragma unroll
            for (int m = 1; m < 64; m <<= 1) {
                rs  += __shfl_xor(rs,  m, 64);
                rs2 += __shfl_xor(rs2, m, 64);
            }
            if (lane == 0) { red[wave] = rs; red[16 + wave] = rs2; }
            WAIT_LGKM(); RAW_BAR();
            float ss = 0.f, ss2 = 0.f;
#pragma unroll
            for (int w = 0; w < 16; ++w) { ss += red[w]; ss2 += red[16 + w]; }
            const float mu   = ss * (1.0f / (float)HW);
            const float var  = ss2 * (1.0f / (float)HW) - mu * mu;
            const float rstd = rsqrtf(var + 1e-5f);
            if (t < HW)
                gbuf[t] = 1.0f / (1.0f + __expf(-((acc - mu) * rstd * wg + bv)));
            WAIT_LGKM(); RAW_BAR();
            const f32x4* gb4 = (const f32x4*)gbuf;
            ga0 = gb4[col0];
            ga1 = gb4[col1];
            acc = 0.f;
        }
    }

    // epilogue: store tile-1 from park (gates in ga0/ga1)
    {
        f32x4* o4t = (f32x4*)(out + (size_t)(blk + 256) * TILE_F);
#pragma unroll
        for (int e = 0; e < NCH; ++e) {
            const f16x4* px = (const f16x4*)xh + e * CH4;
            f32x4* o4 = o4t + e * CH4;
            o4[t] = __builtin_convertvector(px[t], f32x4) * ga0;
            if (wave < 8) {
                o4[1024 + t] = __builtin_convertvector(px[1024 + t], f32x4) * ga1;
            } else if (wave == 8) {
                if (lane < 32)
                    o4[1024 + t] = __builtin_convertvector(px[1024 + t], f32x4) * ga1;
            }
        }
    }
}

extern "C" void kernel_launch(void* const* d_in, const int* in_sizes, int n_in,
                              void* d_out, int out_size, void* d_ws, size_t ws_size,
                              hipStream_t stream) {
    const float* x      = (const float*)d_in[0];
    const float* weight = (const float*)d_in[1];
    const float* bias   = (const float*)d_in[2];
    float* out = (float*)d_out;

    static bool init = false;
    if (!init) {
        (void)hipFuncSetAttribute((const void*)sge_kernel,
                                  hipFuncAttributeMaxDynamicSharedMemorySize,
                                  LDS_TOTAL);
        init = true;
    }
    sge_kernel<<<dim3(256), dim3(1024), LDS_TOTAL, stream>>>(x, weight, bias, out);
}